// Round 2
// baseline (1535.702 us; speedup 1.0000x reference)
//
#include <hip/hip_runtime.h>
#include <math.h>

#define NN 10000
#define NE 100000

typedef float f32x2 __attribute__((ext_vector_type(2)));

static constexpr float C_TANH  = 1.5927f;
static constexpr float SQ3     = 1.7320508075688772f;
static constexpr float H_SCALE = 0.4472135954999579f;   // C_RELU / sqrt(10)
static constexpr float A0      = 0.11785113019775793f;  // sqrt(1/72)
static constexpr float A0S3    = 0.06804138174397717f;  // sqrt(1/216)
static constexpr float B0      = 0.20412414523193154f;  // sqrt(1/24)
static constexpr float B0S3    = 0.11785113019775793f;  // sqrt(1/72)
static constexpr float S32     = 0.1767766952966369f;   // 1/sqrt(32)
static constexpr float S16     = 0.25f;                 // 1/sqrt(16)
static constexpr float S8      = 0.3535533905932738f;   // 1/sqrt(8)

// ---------------------------------------------------------------------------
// Prep: transpose fc*_w2 to column-major (16 contiguous floats per output
// column) with 1/sqrt(16) and the per-region output scales folded in.
// ---------------------------------------------------------------------------
__global__ void prep_kernel(const float* __restrict__ fc1_w2,
                            const float* __restrict__ fc2_w2,
                            float* __restrict__ Ft1,
                            float* __restrict__ Ft2) {
  int t = blockIdx.x * blockDim.x + threadIdx.x;
  if (t < 2304) {
    float s = (t >= 1152 && t < 1728) ? A0S3 : A0;
    s *= 0.25f;
    #pragma unroll
    for (int k = 0; k < 16; ++k) Ft1[t * 16 + k] = fc1_w2[k * 2304 + t] * s;
  } else if (t < 2304 + 576) {
    int j = t - 2304;
    float s = (j >= 256 && j < 384) ? B0S3 : B0;
    s *= 0.25f;
    #pragma unroll
    for (int k = 0; k < 16; ++k) Ft2[j * 16 + k] = fc2_w2[k * 576 + j] * s;
  }
}

// packed 16-wide dot: returns pairwise partial sums (caller folds via hsum or
// keeps accumulating in the packed domain). 2 mul + 6 fma + 1 add = 9 pk ops.
__device__ __forceinline__ f32x2 dotcol2(const float* __restrict__ p,
                                         const f32x2* hp) {
  const float4* c4 = (const float4*)p;
  float4 q0 = c4[0], q1 = c4[1], q2 = c4[2], q3 = c4[3];
  f32x2 a = (f32x2){q0.x, q0.y} * hp[0];
  f32x2 b = (f32x2){q0.z, q0.w} * hp[1];
  a = __builtin_elementwise_fma((f32x2){q1.x, q1.y}, hp[2], a);
  b = __builtin_elementwise_fma((f32x2){q1.z, q1.w}, hp[3], b);
  a = __builtin_elementwise_fma((f32x2){q2.x, q2.y}, hp[4], a);
  b = __builtin_elementwise_fma((f32x2){q2.z, q2.w}, hp[5], b);
  a = __builtin_elementwise_fma((f32x2){q3.x, q3.y}, hp[6], a);
  b = __builtin_elementwise_fma((f32x2){q3.z, q3.w}, hp[7], b);
  return a + b;
}

__device__ __forceinline__ float hsum(f32x2 v) { return v.x + v.y; }

// ---------------------------------------------------------------------------
// Edge kernel: TWO threads per edge (h = t&1 owns output-channel half).
// Edge pairs are adjacent lanes of the same wave -> LDS handoff needs no
// barrier. Weight-column loads are 2-distinct-addresses per wave (cheap).
// ---------------------------------------------------------------------------
__global__ __launch_bounds__(256, 3) void edge_kernel(
    const float* __restrict__ hn, const float* __restrict__ he,
    const float* __restrict__ edge_vec, const float* __restrict__ emb,
    const float* __restrict__ norm, const float* __restrict__ fc1_w1,
    const float* __restrict__ fc2_w1, const int* __restrict__ edge_index,
    const float* __restrict__ Ft1, const float* __restrict__ Ft2,
    float* __restrict__ out_he, float* __restrict__ nf) {
  __shared__ float tsbuf[128 * 49];  // 49: coprime with 32 -> conflict-free
  int t = blockIdx.x * blockDim.x + threadIdx.x;
  int e = t >> 1, h = t & 1;
  if (e >= NE) return;
  int le = threadIdx.x >> 1;
  float* tb = tsbuf + le * 49;

  float em[10];
  #pragma unroll
  for (int m = 0; m < 10; ++m) em[m] = emb[(size_t)e * 10 + m];

  f32x2 hp[8];
  #pragma unroll
  for (int k = 0; k < 8; ++k) {
    float s0 = 0.f, s1 = 0.f;
    #pragma unroll
    for (int m = 0; m < 10; ++m) {
      s0 = fmaf(em[m], fc1_w1[m * 16 + 2 * k], s0);
      s1 = fmaf(em[m], fc1_w1[m * 16 + 2 * k + 1], s1);
    }
    hp[k].x = s0 > 0.f ? s0 * H_SCALE : 0.f;
    hp[k].y = s1 > 0.f ? s1 * H_SCALE : 0.f;
  }

  float ev0 = edge_vec[e * 3 + 0], ev1 = edge_vec[e * 3 + 1],
        ev2 = edge_vec[e * 3 + 2];
  float rn = rsqrtf(fmaf(ev0, ev0, fmaf(ev1, ev1, ev2 * ev2)));
  float sh0 = SQ3 * ev1 * rn, sh1 = SQ3 * ev2 * rn, sh2 = SQ3 * ev0 * rn;

  int src = edge_index[e], dst = edge_index[NE + e];
  const float* rowe = he + (size_t)e * 40;
  const float* rows = hn + (size_t)src * 40;
  const float* rowd = hn + (size_t)dst * 40;

  f32x2 os[8], og[4], osv[4];
  float ovv[4][3];
  #pragma unroll
  for (int w = 0; w < 8; ++w) os[w] = (f32x2){0.f, 0.f};
  #pragma unroll
  for (int w = 0; w < 4; ++w) {
    og[w] = (f32x2){0.f, 0.f};
    osv[w] = (f32x2){0.f, 0.f};
    ovv[w][0] = 0.f; ovv[w][1] = 0.f; ovv[w][2] = 0.f;
  }

  // ---- layer 1, scalar channels (u = 0..47), w-half = h ----
  #pragma unroll 1
  for (int u = 0; u < 48; ++u) {
    const float* r = (u < 16) ? rowe : ((u < 32) ? rows : rowd);
    float x = r[u & 15];
    f32x2 xx = (f32x2){x, x};
    const float* cs_ = Ft1 + (size_t)(u * 16 + h * 8) * 16;
    const float* cg_ = Ft1 + (size_t)(768 + u * 8 + h * 4) * 16;
    const float* cv_ = Ft1 + (size_t)(1728 + u * 8 + h * 4) * 16;
    #pragma unroll
    for (int w = 0; w < 8; ++w)
      os[w] = __builtin_elementwise_fma(xx, dotcol2(cs_ + w * 16, hp), os[w]);
    #pragma unroll
    for (int w = 0; w < 4; ++w)
      og[w] = __builtin_elementwise_fma(xx, dotcol2(cg_ + w * 16, hp), og[w]);
    #pragma unroll
    for (int w = 0; w < 4; ++w)
      osv[w] = __builtin_elementwise_fma(xx, dotcol2(cv_ + w * 16, hp), osv[w]);
  }

  // ---- layer 1, vector channels (u = 0..23) ----
  #pragma unroll 1
  for (int u = 0; u < 24; ++u) {
    const float* r = (u < 8) ? rowe : ((u < 16) ? rows : rowd);
    int uu = u & 7;
    float x0 = r[16 + uu * 3 + 0];
    float x1 = r[16 + uu * 3 + 1];
    float x2 = r[16 + uu * 3 + 2];
    float xvs = fmaf(sh0, x0, fmaf(sh1, x1, sh2 * x2));
    f32x2 xx = (f32x2){xvs, xvs};
    const float* cs_ = Ft1 + (size_t)(1152 + u * 16 + h * 8) * 16;
    const float* cg_ = Ft1 + (size_t)(1536 + u * 8 + h * 4) * 16;
    const float* cv_ = Ft1 + (size_t)(2112 + u * 8 + h * 4) * 16;
    #pragma unroll
    for (int w = 0; w < 8; ++w)
      os[w] = __builtin_elementwise_fma(xx, dotcol2(cs_ + w * 16, hp), os[w]);
    #pragma unroll
    for (int w = 0; w < 4; ++w)
      og[w] = __builtin_elementwise_fma(xx, dotcol2(cg_ + w * 16, hp), og[w]);
    #pragma unroll
    for (int w = 0; w < 4; ++w) {
      float wj = hsum(dotcol2(cv_ + w * 16, hp));
      ovv[w][0] = fmaf(x0, wj, ovv[w][0]);
      ovv[w][1] = fmaf(x1, wj, ovv[w][1]);
      ovv[w][2] = fmaf(x2, wj, ovv[w][2]);
    }
  }

  // ---- nonlinearity; stash this half's layer-2 inputs in LDS ----
  #pragma unroll
  for (int w = 0; w < 8; ++w)
    tb[h * 8 + w] = C_TANH * tanhf(hsum(os[w]));
  #pragma unroll
  for (int w = 0; w < 4; ++w) {
    int wg = h * 4 + w;
    float g = C_TANH * tanhf(hsum(og[w]));
    float sv = hsum(osv[w]);
    float t0 = g * fmaf(sh0, sv, ovv[w][0]);
    float t1 = g * fmaf(sh1, sv, ovv[w][1]);
    float t2 = g * fmaf(sh2, sv, ovv[w][2]);
    tb[16 + wg * 3 + 0] = t0;
    tb[16 + wg * 3 + 1] = t1;
    tb[16 + wg * 3 + 2] = t2;
    tb[40 + wg] = fmaf(sh0, t0, fmaf(sh1, t1, sh2 * t2));
  }

  // h2 (layer-2 hidden) from em
  f32x2 h2p[8];
  #pragma unroll
  for (int k = 0; k < 8; ++k) {
    float s0 = 0.f, s1 = 0.f;
    #pragma unroll
    for (int m = 0; m < 10; ++m) {
      s0 = fmaf(em[m], fc2_w1[m * 16 + 2 * k], s0);
      s1 = fmaf(em[m], fc2_w1[m * 16 + 2 * k + 1], s1);
    }
    h2p[k].x = s0 > 0.f ? s0 * H_SCALE : 0.f;
    h2p[k].y = s1 > 0.f ? s1 * H_SCALE : 0.f;
  }

  f32x2 ds[8], sv2[4];
  float vv2[4][3];
  #pragma unroll
  for (int w = 0; w < 8; ++w) ds[w] = (f32x2){0.f, 0.f};
  #pragma unroll
  for (int w = 0; w < 4; ++w) {
    sv2[w] = (f32x2){0.f, 0.f};
    vv2[w][0] = 0.f; vv2[w][1] = 0.f; vv2[w][2] = 0.f;
  }

  // ---- layer 2, scalar inputs (u = 0..15); partner's tmp via LDS (same
  // wave -> lockstep, no barrier needed) ----
  #pragma unroll 1
  for (int u = 0; u < 16; ++u) {
    float x = tb[u];
    f32x2 xx = (f32x2){x, x};
    const float* cs_ = Ft2 + (size_t)(u * 16 + h * 8) * 16;
    const float* cv_ = Ft2 + (size_t)(384 + u * 8 + h * 4) * 16;
    #pragma unroll
    for (int w = 0; w < 8; ++w)
      ds[w] = __builtin_elementwise_fma(xx, dotcol2(cs_ + w * 16, h2p), ds[w]);
    #pragma unroll
    for (int w = 0; w < 4; ++w)
      sv2[w] = __builtin_elementwise_fma(xx, dotcol2(cv_ + w * 16, h2p), sv2[w]);
  }
  // ---- layer 2, vector inputs (u = 0..7) ----
  #pragma unroll 1
  for (int u = 0; u < 8; ++u) {
    float xt = tb[40 + u];
    float x0 = tb[16 + u * 3 + 0];
    float x1 = tb[16 + u * 3 + 1];
    float x2 = tb[16 + u * 3 + 2];
    f32x2 xx = (f32x2){xt, xt};
    const float* cs_ = Ft2 + (size_t)(256 + u * 16 + h * 8) * 16;
    const float* cv_ = Ft2 + (size_t)(512 + u * 8 + h * 4) * 16;
    #pragma unroll
    for (int w = 0; w < 8; ++w)
      ds[w] = __builtin_elementwise_fma(xx, dotcol2(cs_ + w * 16, h2p), ds[w]);
    #pragma unroll
    for (int w = 0; w < 4; ++w) {
      float wj = hsum(dotcol2(cv_ + w * 16, h2p));
      vv2[w][0] = fmaf(x0, wj, vv2[w][0]);
      vv2[w][1] = fmaf(x1, wj, vv2[w][1]);
      vv2[w][2] = fmaf(x2, wj, vv2[w][2]);
    }
  }

  // ---- this half's he_new channels + scatter into nf[dst] ----
  float nrm = norm[e];
  float* o = out_he + (size_t)e * 40;
  float* nfd = nf + (size_t)dst * 40;
  #pragma unroll
  for (int w = 0; w < 8; ++w) {
    int j = h * 8 + w;
    float val = rowe[j] + hsum(ds[w]);
    o[j] = val;
    unsafeAtomicAdd(nfd + j, val * nrm);
  }
  #pragma unroll
  for (int w = 0; w < 4; ++w) {
    int wg = h * 4 + w;
    float sv = hsum(sv2[w]);
    float v0 = rowe[16 + wg * 3 + 0] + fmaf(sh0, sv, vv2[w][0]);
    float v1 = rowe[16 + wg * 3 + 1] + fmaf(sh1, sv, vv2[w][1]);
    float v2 = rowe[16 + wg * 3 + 2] + fmaf(sh2, sv, vv2[w][2]);
    o[16 + wg * 3 + 0] = v0;
    o[16 + wg * 3 + 1] = v1;
    o[16 + wg * 3 + 2] = v2;
    unsafeAtomicAdd(nfd + 16 + wg * 3 + 0, v0 * nrm);
    unsafeAtomicAdd(nfd + 16 + wg * 3 + 1, v1 * nrm);
    unsafeAtomicAdd(nfd + 16 + wg * 3 + 2, v2 * nrm);
  }
}

// ---------------------------------------------------------------------------
// Node kernel: one thread per node.
// ---------------------------------------------------------------------------
__global__ __launch_bounds__(256) void node_kernel(
    const float* __restrict__ hn, const float* __restrict__ nf,
    const float* __restrict__ wl1_s, const float* __restrict__ wl1_g,
    const float* __restrict__ wl1_v, const float* __restrict__ wl2_s,
    const float* __restrict__ wl2_v, float* __restrict__ out) {
  int n = blockIdx.x * blockDim.x + threadIdx.x;
  if (n >= NN) return;
  const float* rh = hn + (size_t)n * 40;
  const float* rf = nf + (size_t)n * 40;

  float cs[32], cv[16][3];
  #pragma unroll
  for (int u = 0; u < 16; ++u) cs[u] = rh[u];
  #pragma unroll
  for (int u = 0; u < 16; ++u) cs[16 + u] = rf[u];
  #pragma unroll
  for (int u = 0; u < 8; ++u) {
    cv[u][0] = rh[16 + u * 3 + 0];
    cv[u][1] = rh[16 + u * 3 + 1];
    cv[u][2] = rh[16 + u * 3 + 2];
  }
  #pragma unroll
  for (int u = 0; u < 8; ++u) {
    cv[8 + u][0] = rf[16 + u * 3 + 0];
    cv[8 + u][1] = rf[16 + u * 3 + 1];
    cv[8 + u][2] = rf[16 + u * 3 + 2];
  }

  float l1s[16], l1g[8], l1v[8][3];
  #pragma unroll
  for (int w = 0; w < 16; ++w) l1s[w] = 0.f;
  #pragma unroll
  for (int w = 0; w < 8; ++w) {
    l1g[w] = 0.f; l1v[w][0] = 0.f; l1v[w][1] = 0.f; l1v[w][2] = 0.f;
  }
  #pragma unroll
  for (int u = 0; u < 32; ++u) {
    float x = cs[u];
    #pragma unroll
    for (int w = 0; w < 16; ++w) l1s[w] = fmaf(x, wl1_s[u * 16 + w], l1s[w]);
    #pragma unroll
    for (int w = 0; w < 8; ++w) l1g[w] = fmaf(x, wl1_g[u * 8 + w], l1g[w]);
  }
  #pragma unroll
  for (int u = 0; u < 16; ++u) {
    #pragma unroll
    for (int w = 0; w < 8; ++w) {
      float wv = wl1_v[u * 8 + w];
      l1v[w][0] = fmaf(cv[u][0], wv, l1v[w][0]);
      l1v[w][1] = fmaf(cv[u][1], wv, l1v[w][1]);
      l1v[w][2] = fmaf(cv[u][2], wv, l1v[w][2]);
    }
  }

  float gs[16], gv[8][3];
  #pragma unroll
  for (int w = 0; w < 16; ++w) gs[w] = C_TANH * tanhf(l1s[w] * S32);
  #pragma unroll
  for (int w = 0; w < 8; ++w) {
    float g = C_TANH * tanhf(l1g[w] * S32);
    gv[w][0] = g * l1v[w][0] * S16;
    gv[w][1] = g * l1v[w][1] * S16;
    gv[w][2] = g * l1v[w][2] * S16;
  }

  float l2s[16], l2v[8][3];
  #pragma unroll
  for (int v = 0; v < 16; ++v) l2s[v] = 0.f;
  #pragma unroll
  for (int v = 0; v < 8; ++v) { l2v[v][0] = 0.f; l2v[v][1] = 0.f; l2v[v][2] = 0.f; }
  #pragma unroll
  for (int w = 0; w < 16; ++w) {
    float g = gs[w];
    #pragma unroll
    for (int v = 0; v < 16; ++v) l2s[v] = fmaf(g, wl2_s[w * 16 + v], l2s[v]);
  }
  #pragma unroll
  for (int w = 0; w < 8; ++w) {
    #pragma unroll
    for (int v = 0; v < 8; ++v) {
      float wv = wl2_v[w * 8 + v];
      l2v[v][0] = fmaf(gv[w][0], wv, l2v[v][0]);
      l2v[v][1] = fmaf(gv[w][1], wv, l2v[v][1]);
      l2v[v][2] = fmaf(gv[w][2], wv, l2v[v][2]);
    }
  }

  float* o = out + (size_t)n * 40;
  #pragma unroll
  for (int v = 0; v < 16; ++v) o[v] = rh[v] + l2s[v] * S16;
  #pragma unroll
  for (int v = 0; v < 8; ++v) {
    o[16 + v * 3 + 0] = rh[16 + v * 3 + 0] + l2v[v][0] * S8;
    o[16 + v * 3 + 1] = rh[16 + v * 3 + 1] + l2v[v][1] * S8;
    o[16 + v * 3 + 2] = rh[16 + v * 3 + 2] + l2v[v][2] * S8;
  }
}

extern "C" void kernel_launch(void* const* d_in, const int* in_sizes, int n_in,
                              void* d_out, int out_size, void* d_ws,
                              size_t ws_size, hipStream_t stream) {
  const float* hn       = (const float*)d_in[0];
  const float* he       = (const float*)d_in[1];
  const float* edge_vec = (const float*)d_in[2];
  const float* emb      = (const float*)d_in[3];
  const float* norm     = (const float*)d_in[4];
  const float* fc1_w1   = (const float*)d_in[5];
  const float* fc1_w2   = (const float*)d_in[6];
  const float* fc2_w1   = (const float*)d_in[7];
  const float* fc2_w2   = (const float*)d_in[8];
  const float* wl1_s    = (const float*)d_in[9];
  const float* wl1_g    = (const float*)d_in[10];
  const float* wl1_v    = (const float*)d_in[11];
  const float* wl2_s    = (const float*)d_in[12];
  const float* wl2_v    = (const float*)d_in[13];
  const int*   edge_index = (const int*)d_in[14];

  float* Ft1 = (float*)d_ws;           // 2304*16 floats
  float* Ft2 = Ft1 + 2304 * 16;        // 576*16 floats
  float* nf  = Ft2 + 576 * 16;         // NN*40 floats

  hipMemsetAsync(nf, 0, (size_t)NN * 40 * sizeof(float), stream);
  prep_kernel<<<dim3((2880 + 255) / 256), dim3(256), 0, stream>>>(fc1_w2,
                                                                  fc2_w2, Ft1,
                                                                  Ft2);
  float* out = (float*)d_out;
  edge_kernel<<<dim3((2 * NE + 255) / 256), dim3(256), 0, stream>>>(
      hn, he, edge_vec, emb, norm, fc1_w1, fc2_w1, edge_index, Ft1, Ft2,
      out + (size_t)NN * 40, nf);
  node_kernel<<<dim3((NN + 255) / 256), dim3(256), 0, stream>>>(
      hn, nf, wl1_s, wl1_g, wl1_v, wl2_s, wl2_v, out);
}

// Round 3
// 268.113 us; speedup vs baseline: 5.7278x; 5.7278x over previous
//
#include <hip/hip_runtime.h>
#include <hip/hip_bf16.h>
#include <math.h>

#define NN 10000
#define NE 100000
#define NTILES ((NE + 63) / 64)

typedef __attribute__((ext_vector_type(4))) float f32x4;
typedef __attribute__((ext_vector_type(8))) short short8;

static constexpr float C_TANH  = 1.5927f;
static constexpr float SQ3     = 1.7320508075688772f;
static constexpr float H_SCALE = 0.4472135954999579f;   // C_RELU/sqrt(10)
// output-region scales with 1/sqrt(16) folded in
static constexpr float A0Q   = 0.11785113019775793f * 0.25f;  // sqrt(1/72)/4
static constexpr float A0S3Q = 0.06804138174397717f * 0.25f;  // sqrt(1/216)/4
static constexpr float B0Q   = 0.20412414523193154f * 0.25f;  // sqrt(1/24)/4
static constexpr float B0S3Q = 0.11785113019775793f * 0.25f;  // sqrt(1/72)/4
static constexpr float S32 = 0.1767766952966369f;
static constexpr float S16 = 0.25f;
static constexpr float S8  = 0.3535533905932738f;

__device__ __forceinline__ unsigned short f2bf(float f) {
  union { float f; unsigned u; } cv; cv.f = f;
  unsigned r = cv.u + 0x7fffu + ((cv.u >> 16) & 1u);
  return (unsigned short)(r >> 16);
}
__device__ __forceinline__ float bf2f(unsigned short s) {
  return __uint_as_float(((unsigned)s) << 16);
}

// ---------------------------------------------------------------------------
// Prep: build 4 frag-linear bf16 weight blobs (112KB total) in d_ws.
// Blob = sequence of 1KB blocks, one per (kstep, ntile); within a block,
// lane l's 16B = B[K = 32*s + (l>>4)*8 + j][col = nt*16 + (l&15)], j=0..7.
// blocks: [0,72) GEMM-A(L1 main, K=1152,N=32); [72,84) GEMM-B(L1 vv, K=384,N=16);
//         [84,108) GEMM-C(L2 main, K=384,N=32); [108,112) GEMM-D(L2 vv, K=128,N=16)
// ---------------------------------------------------------------------------
__global__ void prep2_kernel(const float* __restrict__ fc1_w2,
                             const float* __restrict__ fc2_w2,
                             unsigned short* __restrict__ wb) {
  int t = blockIdx.x * blockDim.x + threadIdx.x;
  if (t >= 112 * 64) return;
  int lane = t & 63, blk = t >> 6;
  int grp = lane >> 4, c = lane & 15;
  unsigned short* dst = wb + (size_t)blk * 512 + lane * 8;
  int gemm, s, nt;
  if (blk < 72)       { gemm = 0; s = blk >> 1;        nt = blk & 1; }
  else if (blk < 84)  { gemm = 1; s = blk - 72;        nt = 0; }
  else if (blk < 108) { gemm = 2; s = (blk - 84) >> 1; nt = (blk - 84) & 1; }
  else                { gemm = 3; s = blk - 108;       nt = 0; }
  int n = nt * 16 + c;
  #pragma unroll
  for (int j = 0; j < 8; ++j) {
    int K = 32 * s + grp * 8 + j;
    int u = K >> 4, k = K & 15;
    float v = 0.f;
    if (gemm == 0) {
      // u-slots: [0,48) xs, [48,72) xvs ; n: [0,16) out_s, [16,24) out_g, [24,32) svw
      if (n < 16) v = (u < 48) ? A0Q   * fc1_w2[k * 2304 + u * 16 + n]
                               : A0S3Q * fc1_w2[k * 2304 + 1152 + (u - 48) * 16 + n];
      else if (n < 24) { int w = n - 16;
        v = (u < 48) ? A0Q   * fc1_w2[k * 2304 + 768 + u * 8 + w]
                     : A0S3Q * fc1_w2[k * 2304 + 1536 + (u - 48) * 8 + w];
      } else { int w = n - 24;
        v = (u < 48) ? A0Q * fc1_w2[k * 2304 + 1728 + u * 8 + w] : 0.f;
      }
    } else if (gemm == 1) {          // xv_i -> vvw, u' in [0,24)
      v = (n < 8) ? A0Q * fc1_w2[k * 2304 + 2112 + u * 8 + n] : 0.f;
    } else if (gemm == 2) {          // u2: [0,16) tmp_s, [16,24) tmpvs ; n: [0,16) d_s, [16,24) sv2
      if (u < 16) {
        if (n < 16)      v = B0Q * fc2_w2[k * 576 + u * 16 + n];
        else if (n < 24) v = B0Q * fc2_w2[k * 576 + 384 + u * 8 + (n - 16)];
      } else {
        if (n < 16)      v = B0S3Q * fc2_w2[k * 576 + 256 + (u - 16) * 16 + n];
      }
    } else {                          // tmp_v_i -> vv2, u3 in [0,8)
      v = (n < 8) ? B0Q * fc2_w2[k * 576 + 512 + u * 8 + n] : 0.f;
    }
    dst[j] = f2bf(v);
  }
}

// A-fragment: 8 bf16 products x*h[k0+j], packed pairs
__device__ __forceinline__ short8 mk_afrag(float x, const float* hh) {
  union { short8 s8; __hip_bfloat162 h2[4]; } u;
  #pragma unroll
  for (int m = 0; m < 4; ++m)
    u.h2[m] = __float22bfloat162_rn(make_float2(x * hh[2 * m], x * hh[2 * m + 1]));
  return u.s8;
}

// ---------------------------------------------------------------------------
// LDS layout (bytes) — 152576 total
// ---------------------------------------------------------------------------
#define WB_OFF   0        // 112KB weight blobs
#define XS1_OFF  114688   // ushort [64][74]  (xs 48 | xvs 24, pad 2)
#define XV1_OFF  124160   // ushort [64][74]  ([i][24]: he8|src8|dst8, pad 2)
#define H1_OFF   133632   // float  [64][17]
#define H2_OFF   137984   // float  [64][17]
#define SH_OFF   142336   // float  [64][4]
#define EMB_OFF  143360   // float  [64][10]
#define X2S_OFF  145920   // ushort [64][26]  (tmp_s 16 | tmpvs 8, pad 2)
#define X2V_OFF  149248   // ushort [64][26]  ([i][8], pad 2)
#define OUT1_OFF 114688   // float [64][57] overlays XS1/XV1 (after L1 GEMM)
#define OUT2_OFF 114688   // float [64][49] overlays OUT1    (after L2 GEMM)
#define SMEM_BYTES 152576

__global__ __launch_bounds__(256) void edge_mfma_kernel(
    const float* __restrict__ hn, const float* __restrict__ he,
    const float* __restrict__ edge_vec, const float* __restrict__ emb,
    const float* __restrict__ norm, const float* __restrict__ fc1_w1,
    const float* __restrict__ fc2_w1, const int* __restrict__ edge_index,
    const unsigned short* __restrict__ wb, float* __restrict__ out_he,
    float* __restrict__ nf) {
  static __shared__ __align__(16) char smem[SMEM_BYTES];
  const int tid = threadIdx.x;

  // ---- stage weight blobs into LDS once per block ----
  {
    const uint4* g = (const uint4*)wb;
    uint4* d = (uint4*)(smem + WB_OFF);
    for (int c0 = tid; c0 < 114688 / 16; c0 += 256) d[c0] = g[c0];
  }

  const unsigned short* WBu = (const unsigned short*)(smem + WB_OFF);
  unsigned short* XS1u = (unsigned short*)(smem + XS1_OFF);
  unsigned short* XV1u = (unsigned short*)(smem + XV1_OFF);
  float* H1f = (float*)(smem + H1_OFF);
  float* H2f = (float*)(smem + H2_OFF);
  float* SHf = (float*)(smem + SH_OFF);
  float* EMBf = (float*)(smem + EMB_OFF);
  unsigned short* X2Su = (unsigned short*)(smem + X2S_OFF);
  unsigned short* X2Vu = (unsigned short*)(smem + X2V_OFF);
  float* OUT1f = (float*)(smem + OUT1_OFF);
  float* OUT2f = (float*)(smem + OUT2_OFF);

  const int e4 = tid >> 2, part = tid & 3;          // staging/epilogue mapping
  const int wv = tid >> 6, l = tid & 63;            // GEMM mapping
  const int c = l & 15, grp = l >> 4;
  const int e4row = wv * 16 + c;                    // A-operand row (edge)
  const int k0 = (grp & 1) * 8;                     // h-half
  const int du = grp >> 1;                          // u parity offset

  __syncthreads();  // weights ready

  for (int tile = blockIdx.x; tile < NTILES; tile += gridDim.x) {
    const int tb = tile * 64;
    const int e = tb + e4;
    const bool ev = (e < NE);

    // ---------- A: stage raw rows ----------
    if (ev) {
      const float* her = he + (size_t)e * 40;
      int srcn = edge_index[e], dstn = edge_index[NE + e];
      const float* hsr = hn + (size_t)srcn * 40;
      const float* hdr = hn + (size_t)dstn * 40;
      #pragma unroll
      for (int q = 0; q < 10; ++q) {
        int idx = part * 10 + q;
        float vee = her[idx], vs = hsr[idx], vd = hdr[idx];
        if (idx < 16) {
          XS1u[e4 * 74 + idx]      = f2bf(vee);
          XS1u[e4 * 74 + 16 + idx] = f2bf(vs);
          XS1u[e4 * 74 + 32 + idx] = f2bf(vd);
        } else {
          int m = idx - 16, up = m / 3, i = m % 3;
          XV1u[e4 * 74 + i * 24 + up]      = f2bf(vee);
          XV1u[e4 * 74 + i * 24 + 8 + up]  = f2bf(vs);
          XV1u[e4 * 74 + i * 24 + 16 + up] = f2bf(vd);
        }
      }
      if (part < 2) {
        #pragma unroll
        for (int q = 0; q < 5; ++q)
          EMBf[e4 * 10 + part * 5 + q] = emb[(size_t)e * 10 + part * 5 + q];
      }
      if (part == 3) {
        float ev0 = edge_vec[e * 3 + 0], ev1 = edge_vec[e * 3 + 1],
              ev2 = edge_vec[e * 3 + 2];
        float rn = rsqrtf(fmaf(ev0, ev0, fmaf(ev1, ev1, ev2 * ev2)));
        SHf[e4 * 4 + 0] = SQ3 * ev1 * rn;
        SHf[e4 * 4 + 1] = SQ3 * ev2 * rn;
        SHf[e4 * 4 + 2] = SQ3 * ev0 * rn;
      }
    }
    __syncthreads();

    // ---------- C: derived (h1,h2,xvs) ----------
    {
      #pragma unroll
      for (int kk = 0; kk < 4; ++kk) {
        int k = part * 4 + kk;
        float s1 = 0.f, s2 = 0.f;
        #pragma unroll
        for (int m = 0; m < 10; ++m) {
          float em = EMBf[e4 * 10 + m];
          s1 = fmaf(em, fc1_w1[m * 16 + k], s1);
          s2 = fmaf(em, fc2_w1[m * 16 + k], s2);
        }
        H1f[e4 * 17 + k] = s1 > 0.f ? s1 * H_SCALE : 0.f;
        H2f[e4 * 17 + k] = s2 > 0.f ? s2 * H_SCALE : 0.f;
      }
      #pragma unroll
      for (int uu = 0; uu < 6; ++uu) {
        int us = part * 6 + uu;
        float a = 0.f;
        #pragma unroll
        for (int i = 0; i < 3; ++i)
          a = fmaf(bf2f(XV1u[e4 * 74 + i * 24 + us]), SHf[e4 * 4 + i], a);
        XS1u[e4 * 74 + 48 + us] = f2bf(a);
      }
    }
    __syncthreads();

    // ---------- E: layer-1 GEMMs ----------
    float hh[8];
    #pragma unroll
    for (int j = 0; j < 8; ++j) hh[j] = H1f[e4row * 17 + k0 + j];

    f32x4 accA0 = {0.f, 0.f, 0.f, 0.f}, accA1 = {0.f, 0.f, 0.f, 0.f};
    for (int s = 0; s < 36; ++s) {
      float x = bf2f(XS1u[e4row * 74 + 2 * s + du]);
      short8 a = mk_afrag(x, hh);
      short8 b0 = *(const short8*)(WBu + (size_t)(s * 2 + 0) * 512 + l * 8);
      short8 b1 = *(const short8*)(WBu + (size_t)(s * 2 + 1) * 512 + l * 8);
      accA0 = __builtin_amdgcn_mfma_f32_16x16x32_bf16(a, b0, accA0, 0, 0, 0);
      accA1 = __builtin_amdgcn_mfma_f32_16x16x32_bf16(a, b1, accA1, 0, 0, 0);
    }
    f32x4 accB0 = {0.f, 0.f, 0.f, 0.f}, accB1 = {0.f, 0.f, 0.f, 0.f},
          accB2 = {0.f, 0.f, 0.f, 0.f};
    for (int s = 0; s < 12; ++s) {
      short8 b = *(const short8*)(WBu + (size_t)(72 + s) * 512 + l * 8);
      float x0 = bf2f(XV1u[e4row * 74 + 0 * 24 + 2 * s + du]);
      float x1 = bf2f(XV1u[e4row * 74 + 1 * 24 + 2 * s + du]);
      float x2 = bf2f(XV1u[e4row * 74 + 2 * 24 + 2 * s + du]);
      accB0 = __builtin_amdgcn_mfma_f32_16x16x32_bf16(mk_afrag(x0, hh), b, accB0, 0, 0, 0);
      accB1 = __builtin_amdgcn_mfma_f32_16x16x32_bf16(mk_afrag(x1, hh), b, accB1, 0, 0, 0);
      accB2 = __builtin_amdgcn_mfma_f32_16x16x32_bf16(mk_afrag(x2, hh), b, accB2, 0, 0, 0);
    }
    __syncthreads();  // all LDS reads done before OUT1 overlay

    // ---------- F: flush layer-1 D-frags (D: col=l&15, row=(l>>4)*4+r) ----------
    #pragma unroll
    for (int r = 0; r < 4; ++r) {
      int eo = wv * 16 + grp * 4 + r;
      OUT1f[eo * 57 + c]      = accA0[r];
      OUT1f[eo * 57 + 16 + c] = accA1[r];   // [16,24)=out_g, [24,32)=svw
      if (c < 8) {
        OUT1f[eo * 57 + 32 + c * 3 + 0] = accB0[r];
        OUT1f[eo * 57 + 32 + c * 3 + 1] = accB1[r];
        OUT1f[eo * 57 + 32 + c * 3 + 2] = accB2[r];
      }
    }
    __syncthreads();

    // ---------- G: nonlinearity -> layer-2 inputs ----------
    {
      int eg = tid & 63, pg = tid >> 6;
      if (pg < 2) {
        #pragma unroll
        for (int j = 0; j < 8; ++j) {
          int wch = pg * 8 + j;
          X2Su[eg * 26 + wch] = f2bf(C_TANH * tanhf(OUT1f[eg * 57 + wch]));
        }
      } else {
        #pragma unroll
        for (int w4 = 0; w4 < 4; ++w4) {
          int w = (pg - 2) * 4 + w4;
          float g  = C_TANH * tanhf(OUT1f[eg * 57 + 16 + w]);
          float sv = OUT1f[eg * 57 + 24 + w];
          float tvs = 0.f;
          #pragma unroll
          for (int i = 0; i < 3; ++i) {
            float tv = g * fmaf(SHf[eg * 4 + i], sv, OUT1f[eg * 57 + 32 + w * 3 + i]);
            X2Vu[eg * 26 + i * 8 + w] = f2bf(tv);
            tvs = fmaf(SHf[eg * 4 + i], tv, tvs);
          }
          X2Su[eg * 26 + 16 + w] = f2bf(tvs);
        }
      }
    }
    __syncthreads();

    // ---------- H: layer-2 GEMMs ----------
    #pragma unroll
    for (int j = 0; j < 8; ++j) hh[j] = H2f[e4row * 17 + k0 + j];
    f32x4 accC0 = {0.f, 0.f, 0.f, 0.f}, accC1 = {0.f, 0.f, 0.f, 0.f};
    for (int s = 0; s < 12; ++s) {
      float x = bf2f(X2Su[e4row * 26 + 2 * s + du]);
      short8 a = mk_afrag(x, hh);
      short8 b0 = *(const short8*)(WBu + (size_t)(84 + s * 2 + 0) * 512 + l * 8);
      short8 b1 = *(const short8*)(WBu + (size_t)(84 + s * 2 + 1) * 512 + l * 8);
      accC0 = __builtin_amdgcn_mfma_f32_16x16x32_bf16(a, b0, accC0, 0, 0, 0);
      accC1 = __builtin_amdgcn_mfma_f32_16x16x32_bf16(a, b1, accC1, 0, 0, 0);
    }
    f32x4 accD0 = {0.f, 0.f, 0.f, 0.f}, accD1 = {0.f, 0.f, 0.f, 0.f},
          accD2 = {0.f, 0.f, 0.f, 0.f};
    for (int s = 0; s < 4; ++s) {
      short8 b = *(const short8*)(WBu + (size_t)(108 + s) * 512 + l * 8);
      float x0 = bf2f(X2Vu[e4row * 26 + 0 * 8 + 2 * s + du]);
      float x1 = bf2f(X2Vu[e4row * 26 + 1 * 8 + 2 * s + du]);
      float x2 = bf2f(X2Vu[e4row * 26 + 2 * 8 + 2 * s + du]);
      accD0 = __builtin_amdgcn_mfma_f32_16x16x32_bf16(mk_afrag(x0, hh), b, accD0, 0, 0, 0);
      accD1 = __builtin_amdgcn_mfma_f32_16x16x32_bf16(mk_afrag(x1, hh), b, accD1, 0, 0, 0);
      accD2 = __builtin_amdgcn_mfma_f32_16x16x32_bf16(mk_afrag(x2, hh), b, accD2, 0, 0, 0);
    }
    __syncthreads();

    // ---------- I: flush layer-2 ----------
    #pragma unroll
    for (int r = 0; r < 4; ++r) {
      int eo = wv * 16 + grp * 4 + r;
      OUT2f[eo * 49 + c] = accC0[r];
      if (c < 8) {
        OUT2f[eo * 49 + 16 + c] = accC1[r];
        OUT2f[eo * 49 + 24 + c * 3 + 0] = accD0[r];
        OUT2f[eo * 49 + 24 + c * 3 + 1] = accD1[r];
        OUT2f[eo * 49 + 24 + c * 3 + 2] = accD2[r];
      }
    }
    __syncthreads();

    // ---------- J: epilogue ----------
    if (ev) {
      float nrm = norm[e];
      int dd = edge_index[NE + e];
      const float* her = he + (size_t)e * 40;
      float* o = out_he + (size_t)e * 40;
      float* nfd = nf + (size_t)dd * 40;
      #pragma unroll
      for (int q = 0; q < 10; ++q) {
        int j = part * 10 + q;
        float val;
        if (j < 16) {
          val = her[j] + OUT2f[e4 * 49 + j];
        } else {
          int m = j - 16, w = m / 3, i = m % 3;
          val = her[j] + fmaf(SHf[e4 * 4 + i], OUT2f[e4 * 49 + 16 + w],
                              OUT2f[e4 * 49 + 24 + w * 3 + i]);
        }
        o[j] = val;
        unsafeAtomicAdd(nfd + j, val * nrm);
      }
    }
    __syncthreads();  // protect overlay region before next-tile staging
  }
}

// ---------------------------------------------------------------------------
// Node kernel: one thread per node (unchanged from r1).
// ---------------------------------------------------------------------------
__global__ __launch_bounds__(256) void node_kernel(
    const float* __restrict__ hn, const float* __restrict__ nf,
    const float* __restrict__ wl1_s, const float* __restrict__ wl1_g,
    const float* __restrict__ wl1_v, const float* __restrict__ wl2_s,
    const float* __restrict__ wl2_v, float* __restrict__ out) {
  int n = blockIdx.x * blockDim.x + threadIdx.x;
  if (n >= NN) return;
  const float* rh = hn + (size_t)n * 40;
  const float* rf = nf + (size_t)n * 40;

  float cs[32], cv[16][3];
  #pragma unroll
  for (int u = 0; u < 16; ++u) cs[u] = rh[u];
  #pragma unroll
  for (int u = 0; u < 16; ++u) cs[16 + u] = rf[u];
  #pragma unroll
  for (int u = 0; u < 8; ++u) {
    cv[u][0] = rh[16 + u * 3 + 0];
    cv[u][1] = rh[16 + u * 3 + 1];
    cv[u][2] = rh[16 + u * 3 + 2];
  }
  #pragma unroll
  for (int u = 0; u < 8; ++u) {
    cv[8 + u][0] = rf[16 + u * 3 + 0];
    cv[8 + u][1] = rf[16 + u * 3 + 1];
    cv[8 + u][2] = rf[16 + u * 3 + 2];
  }

  float l1s[16], l1g[8], l1v[8][3];
  #pragma unroll
  for (int w = 0; w < 16; ++w) l1s[w] = 0.f;
  #pragma unroll
  for (int w = 0; w < 8; ++w) {
    l1g[w] = 0.f; l1v[w][0] = 0.f; l1v[w][1] = 0.f; l1v[w][2] = 0.f;
  }
  #pragma unroll
  for (int u = 0; u < 32; ++u) {
    float x = cs[u];
    #pragma unroll
    for (int w = 0; w < 16; ++w) l1s[w] = fmaf(x, wl1_s[u * 16 + w], l1s[w]);
    #pragma unroll
    for (int w = 0; w < 8; ++w) l1g[w] = fmaf(x, wl1_g[u * 8 + w], l1g[w]);
  }
  #pragma unroll
  for (int u = 0; u < 16; ++u) {
    #pragma unroll
    for (int w = 0; w < 8; ++w) {
      float wv = wl1_v[u * 8 + w];
      l1v[w][0] = fmaf(cv[u][0], wv, l1v[w][0]);
      l1v[w][1] = fmaf(cv[u][1], wv, l1v[w][1]);
      l1v[w][2] = fmaf(cv[u][2], wv, l1v[w][2]);
    }
  }

  float gs[16], gv[8][3];
  #pragma unroll
  for (int w = 0; w < 16; ++w) gs[w] = C_TANH * tanhf(l1s[w] * S32);
  #pragma unroll
  for (int w = 0; w < 8; ++w) {
    float g = C_TANH * tanhf(l1g[w] * S32);
    gv[w][0] = g * l1v[w][0] * S16;
    gv[w][1] = g * l1v[w][1] * S16;
    gv[w][2] = g * l1v[w][2] * S16;
  }

  float l2s[16], l2v[8][3];
  #pragma unroll
  for (int v = 0; v < 16; ++v) l2s[v] = 0.f;
  #pragma unroll
  for (int v = 0; v < 8; ++v) { l2v[v][0] = 0.f; l2v[v][1] = 0.f; l2v[v][2] = 0.f; }
  #pragma unroll
  for (int w = 0; w < 16; ++w) {
    float g = gs[w];
    #pragma unroll
    for (int v = 0; v < 16; ++v) l2s[v] = fmaf(g, wl2_s[w * 16 + v], l2s[v]);
  }
  #pragma unroll
  for (int w = 0; w < 8; ++w) {
    #pragma unroll
    for (int v = 0; v < 8; ++v) {
      float wv = wl2_v[w * 8 + v];
      l2v[v][0] = fmaf(gv[w][0], wv, l2v[v][0]);
      l2v[v][1] = fmaf(gv[w][1], wv, l2v[v][1]);
      l2v[v][2] = fmaf(gv[w][2], wv, l2v[v][2]);
    }
  }

  float* o = out + (size_t)n * 40;
  #pragma unroll
  for (int v = 0; v < 16; ++v) o[v] = rh[v] + l2s[v] * S16;
  #pragma unroll
  for (int v = 0; v < 8; ++v) {
    o[16 + v * 3 + 0] = rh[16 + v * 3 + 0] + l2v[v][0] * S8;
    o[16 + v * 3 + 1] = rh[16 + v * 3 + 1] + l2v[v][1] * S8;
    o[16 + v * 3 + 2] = rh[16 + v * 3 + 2] + l2v[v][2] * S8;
  }
}

extern "C" void kernel_launch(void* const* d_in, const int* in_sizes, int n_in,
                              void* d_out, int out_size, void* d_ws,
                              size_t ws_size, hipStream_t stream) {
  const float* hn       = (const float*)d_in[0];
  const float* he       = (const float*)d_in[1];
  const float* edge_vec = (const float*)d_in[2];
  const float* emb      = (const float*)d_in[3];
  const float* norm     = (const float*)d_in[4];
  const float* fc1_w1   = (const float*)d_in[5];
  const float* fc1_w2   = (const float*)d_in[6];
  const float* fc2_w1   = (const float*)d_in[7];
  const float* fc2_w2   = (const float*)d_in[8];
  const float* wl1_s    = (const float*)d_in[9];
  const float* wl1_g    = (const float*)d_in[10];
  const float* wl1_v    = (const float*)d_in[11];
  const float* wl2_s    = (const float*)d_in[12];
  const float* wl2_v    = (const float*)d_in[13];
  const int*   edge_index = (const int*)d_in[14];

  unsigned short* wb = (unsigned short*)d_ws;               // 112KB blobs
  float* nf = (float*)((char*)d_ws + 131072);               // NN*40 f32

  hipMemsetAsync(nf, 0, (size_t)NN * 40 * sizeof(float), stream);
  prep2_kernel<<<dim3((112 * 64 + 255) / 256), dim3(256), 0, stream>>>(
      fc1_w2, fc2_w2, wb);
  float* out = (float*)d_out;
  edge_mfma_kernel<<<dim3(256), dim3(256), 0, stream>>>(
      hn, he, edge_vec, emb, norm, fc1_w1, fc2_w1, edge_index, wb,
      out + (size_t)NN * 40, nf);
  node_kernel<<<dim3((NN + 255) / 256), dim3(256), 0, stream>>>(
      hn, nf, wl1_s, wl1_g, wl1_v, wl2_s, wl2_v, out);
}

// Round 8
// 215.662 us; speedup vs baseline: 7.1209x; 1.2432x over previous
//
#include <hip/hip_runtime.h>
#include <hip/hip_bf16.h>
#include <math.h>

#define NN 10000
#define NE 100000
#define NBLK2 ((NE + 63) / 64)   // 1563 blocks, 64 edges (4 waves x 16)

typedef __attribute__((ext_vector_type(4))) float f32x4;
typedef __attribute__((ext_vector_type(8))) short short8;

static constexpr float C_TANH  = 1.5927f;
static constexpr float SQ3     = 1.7320508075688772f;
static constexpr float H_SCALE = 0.4472135954999579f;   // C_RELU/sqrt(10)
// output-region scales with 1/sqrt(16) folded in
static constexpr float A0Q   = 0.11785113019775793f * 0.25f;  // sqrt(1/72)/4
static constexpr float A0S3Q = 0.06804138174397717f * 0.25f;  // sqrt(1/216)/4
static constexpr float B0Q   = 0.20412414523193154f * 0.25f;  // sqrt(1/24)/4
static constexpr float B0S3Q = 0.11785113019775793f * 0.25f;  // sqrt(1/72)/4
static constexpr float S32 = 0.1767766952966369f;
static constexpr float S16 = 0.25f;
static constexpr float S8  = 0.3535533905932738f;
// s32 fixed-point scale for deterministic nf segment-sum.
static constexpr float FXS = 32768.0f;
static constexpr float FXI = 3.0517578125e-05f;  // 1/32768

__device__ __forceinline__ unsigned short f2bf(float f) {
  union { float f; unsigned u; } cv; cv.f = f;
  unsigned r = cv.u + 0x7fffu + ((cv.u >> 16) & 1u);
  return (unsigned short)(r >> 16);
}
__device__ __forceinline__ float bf2f(unsigned short s) {
  return __uint_as_float(((unsigned)s) << 16);
}

// ---------------------------------------------------------------------------
// Prep: 4 frag-linear bf16 weight blobs (112KB) in d_ws (unchanged since r3).
// ---------------------------------------------------------------------------
__global__ void prep2_kernel(const float* __restrict__ fc1_w2,
                             const float* __restrict__ fc2_w2,
                             unsigned short* __restrict__ wb) {
  int t = blockIdx.x * blockDim.x + threadIdx.x;
  if (t >= 112 * 64) return;
  int lane = t & 63, blk = t >> 6;
  int grp = lane >> 4, c = lane & 15;
  unsigned short* dst = wb + (size_t)blk * 512 + lane * 8;
  int gemm, s, nt;
  if (blk < 72)       { gemm = 0; s = blk >> 1;        nt = blk & 1; }
  else if (blk < 84)  { gemm = 1; s = blk - 72;        nt = 0; }
  else if (blk < 108) { gemm = 2; s = (blk - 84) >> 1; nt = (blk - 84) & 1; }
  else                { gemm = 3; s = blk - 108;       nt = 0; }
  int n = nt * 16 + c;
  #pragma unroll
  for (int j = 0; j < 8; ++j) {
    int K = 32 * s + grp * 8 + j;
    int u = K >> 4, k = K & 15;
    float v = 0.f;
    if (gemm == 0) {
      if (n < 16) v = (u < 48) ? A0Q   * fc1_w2[k * 2304 + u * 16 + n]
                               : A0S3Q * fc1_w2[k * 2304 + 1152 + (u - 48) * 16 + n];
      else if (n < 24) { int w = n - 16;
        v = (u < 48) ? A0Q   * fc1_w2[k * 2304 + 768 + u * 8 + w]
                     : A0S3Q * fc1_w2[k * 2304 + 1536 + (u - 48) * 8 + w];
      } else { int w = n - 24;
        v = (u < 48) ? A0Q * fc1_w2[k * 2304 + 1728 + u * 8 + w] : 0.f;
      }
    } else if (gemm == 1) {
      v = (n < 8) ? A0Q * fc1_w2[k * 2304 + 2112 + u * 8 + n] : 0.f;
    } else if (gemm == 2) {
      if (u < 16) {
        if (n < 16)      v = B0Q * fc2_w2[k * 576 + u * 16 + n];
        else if (n < 24) v = B0Q * fc2_w2[k * 576 + 384 + u * 8 + (n - 16)];
      } else {
        if (n < 16)      v = B0S3Q * fc2_w2[k * 576 + 256 + (u - 16) * 16 + n];
      }
    } else {
      v = (n < 8) ? B0Q * fc2_w2[k * 576 + 512 + u * 8 + n] : 0.f;
    }
    dst[j] = f2bf(v);
  }
}

// A-fragment: 8 bf16 products x*h[k0+j], packed pairs
__device__ __forceinline__ short8 mk_afrag(float x, const float* hh) {
  union { short8 s8; __hip_bfloat162 h2[4]; } u;
  #pragma unroll
  for (int m = 0; m < 4; ++m)
    u.h2[m] = __float22bfloat162_rn(make_float2(x * hh[2 * m], x * hh[2 * m + 1]));
  return u.s8;
}

// ---------------------------------------------------------------------------
// Edge kernel: 256 threads = 4 waves; each wave owns 16 edges and a DEDICATED
// 15616B LDS slice with NO region overlays (OUT1/OUT2 have their own space —
// the aliased-overlay WAR hazard is the prime suspect for the r4-r7
// nondeterminism). Full __syncthreads() at every phase boundary.
// 62.4KB LDS/block -> 2 blocks/CU (8 waves/CU).
// ---------------------------------------------------------------------------
#define XS1_OFF  0        // ushort [16][74]  (xs 48 | xvs 24, pad 2)
#define XV1_OFF  2368     // ushort [16][74]  ([i][24]: he8|src8|dst8)
#define H1_OFF   4736     // float  [16][17]
#define H2_OFF   5824     // float  [16][17]
#define SH_OFF   6912     // float  [16][4]
#define X2S_OFF  7168     // ushort [16][26]  (tmp_s 16 | tmpvs 8, pad 2)
#define X2V_OFF  8000     // ushort [16][26]  ([i][8])
#define OUT1_OFF 8832     // float  [16][57]  DEDICATED (no overlay)
#define OUT2_OFF 12480    // float  [16][49]  DEDICATED (no overlay)
#define SLICE    15616
#define SMEM_BYTES (4 * SLICE)

__global__ __launch_bounds__(256, 2) void edge_mfma_kernel(
    const float* __restrict__ hn, const float* __restrict__ he,
    const float* __restrict__ edge_vec, const float* __restrict__ emb,
    const float* __restrict__ norm, const float* __restrict__ fc1_w1,
    const float* __restrict__ fc2_w1, const int* __restrict__ edge_index,
    const unsigned short* __restrict__ wb, float* __restrict__ out_he,
    int* __restrict__ nfq) {
  __shared__ __align__(16) char smem[SMEM_BYTES];
  const int tid = threadIdx.x;
  const int wv = tid >> 6, l = tid & 63;
  char* sw = smem + wv * SLICE;              // this wave's slice
  unsigned short* XS1u = (unsigned short*)(sw + XS1_OFF);
  unsigned short* XV1u = (unsigned short*)(sw + XV1_OFF);
  float* H1f = (float*)(sw + H1_OFF);
  float* H2f = (float*)(sw + H2_OFF);
  float* SHf = (float*)(sw + SH_OFF);
  unsigned short* X2Su = (unsigned short*)(sw + X2S_OFF);
  unsigned short* X2Vu = (unsigned short*)(sw + X2V_OFF);
  float* OUT1f = (float*)(sw + OUT1_OFF);
  float* OUT2f = (float*)(sw + OUT2_OFF);

  const int e4 = l >> 2, part = l & 3;       // staging/epilogue mapping
  const int c = l & 15, grp = l >> 4;        // GEMM mapping
  const int k0 = (grp & 1) * 8;              // h-half for A-frag
  const int du = grp >> 1;                   // u parity offset
  const int e = blockIdx.x * 64 + wv * 16 + e4;
  const int eld = (e < NE) ? e : (NE - 1);   // clamped loads; stores predicated
  const short8* wbv = (const short8*)wb;

  // ---------- A: stage raw rows ----------
  {
    const float* her = he + (size_t)eld * 40;
    int srcn = edge_index[eld], dstn = edge_index[NE + eld];
    const float* hsr = hn + (size_t)srcn * 40;
    const float* hdr = hn + (size_t)dstn * 40;
    #pragma unroll
    for (int q = 0; q < 10; ++q) {
      int idx = part * 10 + q;
      float vee = her[idx], vs = hsr[idx], vd = hdr[idx];
      if (idx < 16) {
        XS1u[e4 * 74 + idx]      = f2bf(vee);
        XS1u[e4 * 74 + 16 + idx] = f2bf(vs);
        XS1u[e4 * 74 + 32 + idx] = f2bf(vd);
      } else {
        int m = idx - 16, up = m / 3, i = m % 3;
        XV1u[e4 * 74 + i * 24 + up]      = f2bf(vee);
        XV1u[e4 * 74 + i * 24 + 8 + up]  = f2bf(vs);
        XV1u[e4 * 74 + i * 24 + 16 + up] = f2bf(vd);
      }
    }
    if (part == 3) {
      float ev0 = edge_vec[eld * 3 + 0], ev1 = edge_vec[eld * 3 + 1],
            ev2 = edge_vec[eld * 3 + 2];
      float rn = rsqrtf(fmaf(ev0, ev0, fmaf(ev1, ev1, ev2 * ev2)));
      SHf[e4 * 4 + 0] = SQ3 * ev1 * rn;
      SHf[e4 * 4 + 1] = SQ3 * ev2 * rn;
      SHf[e4 * 4 + 2] = SQ3 * ev0 * rn;
    }
  }
  float em[10];
  #pragma unroll
  for (int m = 0; m < 10; ++m) em[m] = emb[(size_t)eld * 10 + m];
  __syncthreads();

  // ---------- C: derived (h1,h2 from em; xvs from XV1+SH) ----------
  {
    #pragma unroll
    for (int kk = 0; kk < 4; ++kk) {
      int k = part * 4 + kk;
      float s1 = 0.f, s2 = 0.f;
      #pragma unroll
      for (int m = 0; m < 10; ++m) {
        s1 = fmaf(em[m], fc1_w1[m * 16 + k], s1);
        s2 = fmaf(em[m], fc2_w1[m * 16 + k], s2);
      }
      H1f[e4 * 17 + k] = s1 > 0.f ? s1 * H_SCALE : 0.f;
      H2f[e4 * 17 + k] = s2 > 0.f ? s2 * H_SCALE : 0.f;
    }
    #pragma unroll
    for (int uu = 0; uu < 6; ++uu) {
      int us = part * 6 + uu;
      float a = 0.f;
      #pragma unroll
      for (int i = 0; i < 3; ++i)
        a = fmaf(bf2f(XV1u[e4 * 74 + i * 24 + us]), SHf[e4 * 4 + i], a);
      XS1u[e4 * 74 + 48 + us] = f2bf(a);
    }
  }
  __syncthreads();

  // ---------- E: layer-1 GEMMs (B from global) ----------
  float hh[8];
  #pragma unroll
  for (int j = 0; j < 8; ++j) hh[j] = H1f[c * 17 + k0 + j];

  f32x4 accA0 = {0.f, 0.f, 0.f, 0.f}, accA1 = {0.f, 0.f, 0.f, 0.f};
  #pragma unroll 6
  for (int s = 0; s < 36; ++s) {
    float x = bf2f(XS1u[c * 74 + 2 * s + du]);
    short8 a = mk_afrag(x, hh);
    short8 b0 = wbv[(size_t)(s * 2 + 0) * 64 + l];
    short8 b1 = wbv[(size_t)(s * 2 + 1) * 64 + l];
    accA0 = __builtin_amdgcn_mfma_f32_16x16x32_bf16(a, b0, accA0, 0, 0, 0);
    accA1 = __builtin_amdgcn_mfma_f32_16x16x32_bf16(a, b1, accA1, 0, 0, 0);
  }
  f32x4 accB0 = {0.f, 0.f, 0.f, 0.f}, accB1 = {0.f, 0.f, 0.f, 0.f},
        accB2 = {0.f, 0.f, 0.f, 0.f};
  #pragma unroll 4
  for (int s = 0; s < 12; ++s) {
    short8 b = wbv[(size_t)(72 + s) * 64 + l];
    float x0 = bf2f(XV1u[c * 74 + 0 * 24 + 2 * s + du]);
    float x1 = bf2f(XV1u[c * 74 + 1 * 24 + 2 * s + du]);
    float x2 = bf2f(XV1u[c * 74 + 2 * 24 + 2 * s + du]);
    accB0 = __builtin_amdgcn_mfma_f32_16x16x32_bf16(mk_afrag(x0, hh), b, accB0, 0, 0, 0);
    accB1 = __builtin_amdgcn_mfma_f32_16x16x32_bf16(mk_afrag(x1, hh), b, accB1, 0, 0, 0);
    accB2 = __builtin_amdgcn_mfma_f32_16x16x32_bf16(mk_afrag(x2, hh), b, accB2, 0, 0, 0);
  }
  __syncthreads();

  // ---------- F: flush layer-1 D-frags (D: col=l&15, row=(l>>4)*4+r) ----------
  #pragma unroll
  for (int r = 0; r < 4; ++r) {
    int eo = grp * 4 + r;
    OUT1f[eo * 57 + c]      = accA0[r];
    OUT1f[eo * 57 + 16 + c] = accA1[r];   // [16,24)=out_g, [24,32)=svw
    if (c < 8) {
      OUT1f[eo * 57 + 32 + c * 3 + 0] = accB0[r];
      OUT1f[eo * 57 + 32 + c * 3 + 1] = accB1[r];
      OUT1f[eo * 57 + 32 + c * 3 + 2] = accB2[r];
    }
  }
  __syncthreads();

  // ---------- G: nonlinearity -> layer-2 inputs ----------
  {
    #pragma unroll
    for (int j = 0; j < 4; ++j) {
      int wch = part * 4 + j;
      X2Su[e4 * 26 + wch] = f2bf(C_TANH * tanhf(OUT1f[e4 * 57 + wch]));
    }
    #pragma unroll
    for (int j = 0; j < 2; ++j) {
      int w = part * 2 + j;
      float g  = C_TANH * tanhf(OUT1f[e4 * 57 + 16 + w]);
      float sv = OUT1f[e4 * 57 + 24 + w];
      float tvs = 0.f;
      #pragma unroll
      for (int i = 0; i < 3; ++i) {
        float tv = g * fmaf(SHf[e4 * 4 + i], sv, OUT1f[e4 * 57 + 32 + w * 3 + i]);
        X2Vu[e4 * 26 + i * 8 + w] = f2bf(tv);
        tvs = fmaf(SHf[e4 * 4 + i], tv, tvs);
      }
      X2Su[e4 * 26 + 16 + w] = f2bf(tvs);
    }
  }
  __syncthreads();

  // ---------- H: layer-2 GEMMs ----------
  #pragma unroll
  for (int j = 0; j < 8; ++j) hh[j] = H2f[c * 17 + k0 + j];
  f32x4 accC0 = {0.f, 0.f, 0.f, 0.f}, accC1 = {0.f, 0.f, 0.f, 0.f};
  #pragma unroll 4
  for (int s = 0; s < 12; ++s) {
    float x = bf2f(X2Su[c * 26 + 2 * s + du]);
    short8 a = mk_afrag(x, hh);
    short8 b0 = wbv[(size_t)(84 + s * 2 + 0) * 64 + l];
    short8 b1 = wbv[(size_t)(84 + s * 2 + 1) * 64 + l];
    accC0 = __builtin_amdgcn_mfma_f32_16x16x32_bf16(a, b0, accC0, 0, 0, 0);
    accC1 = __builtin_amdgcn_mfma_f32_16x16x32_bf16(a, b1, accC1, 0, 0, 0);
  }
  f32x4 accD0 = {0.f, 0.f, 0.f, 0.f}, accD1 = {0.f, 0.f, 0.f, 0.f},
        accD2 = {0.f, 0.f, 0.f, 0.f};
  #pragma unroll
  for (int s = 0; s < 4; ++s) {
    short8 b = wbv[(size_t)(108 + s) * 64 + l];
    float x0 = bf2f(X2Vu[c * 26 + 0 * 8 + 2 * s + du]);
    float x1 = bf2f(X2Vu[c * 26 + 1 * 8 + 2 * s + du]);
    float x2 = bf2f(X2Vu[c * 26 + 2 * 8 + 2 * s + du]);
    accD0 = __builtin_amdgcn_mfma_f32_16x16x32_bf16(mk_afrag(x0, hh), b, accD0, 0, 0, 0);
    accD1 = __builtin_amdgcn_mfma_f32_16x16x32_bf16(mk_afrag(x1, hh), b, accD1, 0, 0, 0);
    accD2 = __builtin_amdgcn_mfma_f32_16x16x32_bf16(mk_afrag(x2, hh), b, accD2, 0, 0, 0);
  }
  __syncthreads();

  // ---------- I: flush layer-2 ----------
  #pragma unroll
  for (int r = 0; r < 4; ++r) {
    int eo = grp * 4 + r;
    OUT2f[eo * 49 + c] = accC0[r];
    if (c < 8) {
      OUT2f[eo * 49 + 16 + c] = accC1[r];
      OUT2f[eo * 49 + 24 + c * 3 + 0] = accD0[r];
      OUT2f[eo * 49 + 24 + c * 3 + 1] = accD1[r];
      OUT2f[eo * 49 + 24 + c * 3 + 2] = accD2[r];
    }
  }
  __syncthreads();

  // ---------- J: epilogue (predicated; s32 fixed-point scatter) ----------
  if (e < NE) {
    float nrm = norm[e];
    int dd = edge_index[NE + e];
    const float* her = he + (size_t)e * 40;
    float* o = out_he + (size_t)e * 40;
    int* nfd = nfq + (size_t)dd * 40;
    #pragma unroll
    for (int q = 0; q < 10; ++q) {
      int j = part * 10 + q;
      float val;
      if (j < 16) {
        val = her[j] + OUT2f[e4 * 49 + j];
      } else {
        int m = j - 16, w = m / 3, i = m % 3;
        val = her[j] + fmaf(SHf[e4 * 4 + i], OUT2f[e4 * 49 + 16 + w],
                            OUT2f[e4 * 49 + 24 + w * 3 + i]);
      }
      o[j] = val;
      int qv = (int)lrintf(val * nrm * FXS);
      atomicAdd(nfd + j, qv);
    }
  }
}

// ---------------------------------------------------------------------------
// Node kernel: r3's proven ONE-thread-per-node version; only change is the
// fixed-point nf conversion on input.
// ---------------------------------------------------------------------------
__global__ __launch_bounds__(256) void node_kernel(
    const float* __restrict__ hn, const int* __restrict__ nfq,
    const float* __restrict__ wl1_s, const float* __restrict__ wl1_g,
    const float* __restrict__ wl1_v, const float* __restrict__ wl2_s,
    const float* __restrict__ wl2_v, float* __restrict__ out) {
  int n = blockIdx.x * blockDim.x + threadIdx.x;
  if (n >= NN) return;
  const float* rh = hn + (size_t)n * 40;
  const int* rq = nfq + (size_t)n * 40;

  float cs[32], cv[16][3];
  #pragma unroll
  for (int u = 0; u < 16; ++u) cs[u] = rh[u];
  #pragma unroll
  for (int u = 0; u < 16; ++u) cs[16 + u] = (float)rq[u] * FXI;
  #pragma unroll
  for (int u = 0; u < 8; ++u) {
    cv[u][0] = rh[16 + u * 3 + 0];
    cv[u][1] = rh[16 + u * 3 + 1];
    cv[u][2] = rh[16 + u * 3 + 2];
    cv[8 + u][0] = (float)rq[16 + u * 3 + 0] * FXI;
    cv[8 + u][1] = (float)rq[16 + u * 3 + 1] * FXI;
    cv[8 + u][2] = (float)rq[16 + u * 3 + 2] * FXI;
  }

  float l1s[16], l1g[8], l1v[8][3];
  #pragma unroll
  for (int w = 0; w < 16; ++w) l1s[w] = 0.f;
  #pragma unroll
  for (int w = 0; w < 8; ++w) {
    l1g[w] = 0.f; l1v[w][0] = 0.f; l1v[w][1] = 0.f; l1v[w][2] = 0.f;
  }
  #pragma unroll
  for (int u = 0; u < 32; ++u) {
    float x = cs[u];
    #pragma unroll
    for (int w = 0; w < 16; ++w) l1s[w] = fmaf(x, wl1_s[u * 16 + w], l1s[w]);
    #pragma unroll
    for (int w = 0; w < 8; ++w) l1g[w] = fmaf(x, wl1_g[u * 8 + w], l1g[w]);
  }
  #pragma unroll
  for (int u = 0; u < 16; ++u) {
    #pragma unroll
    for (int w = 0; w < 8; ++w) {
      float wv = wl1_v[u * 8 + w];
      l1v[w][0] = fmaf(cv[u][0], wv, l1v[w][0]);
      l1v[w][1] = fmaf(cv[u][1], wv, l1v[w][1]);
      l1v[w][2] = fmaf(cv[u][2], wv, l1v[w][2]);
    }
  }

  float gs[16], gv[8][3];
  #pragma unroll
  for (int w = 0; w < 16; ++w) gs[w] = C_TANH * tanhf(l1s[w] * S32);
  #pragma unroll
  for (int w = 0; w < 8; ++w) {
    float g = C_TANH * tanhf(l1g[w] * S32);
    gv[w][0] = g * l1v[w][0] * S16;
    gv[w][1] = g * l1v[w][1] * S16;
    gv[w][2] = g * l1v[w][2] * S16;
  }

  float l2s[16], l2v[8][3];
  #pragma unroll
  for (int v = 0; v < 16; ++v) l2s[v] = 0.f;
  #pragma unroll
  for (int v = 0; v < 8; ++v) { l2v[v][0] = 0.f; l2v[v][1] = 0.f; l2v[v][2] = 0.f; }
  #pragma unroll
  for (int w = 0; w < 16; ++w) {
    float g = gs[w];
    #pragma unroll
    for (int v = 0; v < 16; ++v) l2s[v] = fmaf(g, wl2_s[w * 16 + v], l2s[v]);
  }
  #pragma unroll
  for (int w = 0; w < 8; ++w) {
    #pragma unroll
    for (int v = 0; v < 8; ++v) {
      float wv = wl2_v[w * 8 + v];
      l2v[v][0] = fmaf(gv[w][0], wv, l2v[v][0]);
      l2v[v][1] = fmaf(gv[w][1], wv, l2v[v][1]);
      l2v[v][2] = fmaf(gv[w][2], wv, l2v[v][2]);
    }
  }

  float* o = out + (size_t)n * 40;
  #pragma unroll
  for (int v = 0; v < 16; ++v) o[v] = rh[v] + l2s[v] * S16;
  #pragma unroll
  for (int v = 0; v < 8; ++v) {
    o[16 + v * 3 + 0] = rh[16 + v * 3 + 0] + l2v[v][0] * S8;
    o[16 + v * 3 + 1] = rh[16 + v * 3 + 1] + l2v[v][1] * S8;
    o[16 + v * 3 + 2] = rh[16 + v * 3 + 2] + l2v[v][2] * S8;
  }
}

extern "C" void kernel_launch(void* const* d_in, const int* in_sizes, int n_in,
                              void* d_out, int out_size, void* d_ws,
                              size_t ws_size, hipStream_t stream) {
  const float* hn       = (const float*)d_in[0];
  const float* he       = (const float*)d_in[1];
  const float* edge_vec = (const float*)d_in[2];
  const float* emb      = (const float*)d_in[3];
  const float* norm     = (const float*)d_in[4];
  const float* fc1_w1   = (const float*)d_in[5];
  const float* fc1_w2   = (const float*)d_in[6];
  const float* fc2_w1   = (const float*)d_in[7];
  const float* fc2_w2   = (const float*)d_in[8];
  const float* wl1_s    = (const float*)d_in[9];
  const float* wl1_g    = (const float*)d_in[10];
  const float* wl1_v    = (const float*)d_in[11];
  const float* wl2_s    = (const float*)d_in[12];
  const float* wl2_v    = (const float*)d_in[13];
  const int*   edge_index = (const int*)d_in[14];

  unsigned short* wb = (unsigned short*)d_ws;            // 112KB blobs
  int* nfq = (int*)((char*)d_ws + 131072);               // NN*40 s32 (1.6MB)

  hipMemsetAsync(nfq, 0, (size_t)NN * 40 * sizeof(int), stream);
  prep2_kernel<<<dim3((112 * 64 + 255) / 256), dim3(256), 0, stream>>>(
      fc1_w2, fc2_w2, wb);
  float* out = (float*)d_out;
  edge_mfma_kernel<<<dim3(NBLK2), dim3(256), 0, stream>>>(
      hn, he, edge_vec, emb, norm, fc1_w1, fc2_w1, edge_index, wb,
      out + (size_t)NN * 40, nfq);
  node_kernel<<<dim3((NN + 255) / 256), dim3(256), 0, stream>>>(
      hn, nfq, wl1_s, wl1_g, wl1_v, wl2_s, wl2_v, out);
}